// Round 9
// baseline (504.548 us; speedup 1.0000x reference)
//
#include <hip/hip_runtime.h>

// SerializedMamba on MI355X (gfx950).
// R20: 8-phase GEMM (m201 template port) for in_proj + FFN1. R14-R19: six
//      2-phase variants all pinned at 19-21% MfmaUtil = the measured 2-phase
//      structural ceiling (m230/m233). gemm_8ph: 256x256 tile, BK=64, 8 waves
//      (2Mx4N, per-wave 128x64), 2 K-tile LDS dbuf (128KB), 16 MFMA/phase by
//      (mh,ks) quadrant, B-frags register-cached. 16 stage-units (8KB = 1
//      gld_lds16/thread) per 2-K-tile iteration; schedule (unit: last-read ->
//      staged): derived so stage >= last-read+1 (barrier-chain overwrite
//      safety) and stage <= covering-vmcnt-3 (landing):
//        ph1: bufB.A1,A3<-kt(2i+1) | ph3: bufA.B0,B1<-kt(2i+2)
//        ph4: bufA.B2,B3,A0 + vmcnt(5) | ph5: bufA.A2,A1,A3
//        ph7: bufB.B0,B1,B2<-kt(2i+3) | ph8: bufB.B3,A0,A2 + vmcnt(6)
//      vmcnt never 0 mid-loop (T4); drain only in final iteration (prefetch
//      guards off there -- counted values verified unsafe in that case).
//      setprio(1) around MFMA cluster (T5). R14's 3-bit XOR LDS bijection
//      (conflicts 0). out_proj/FFN2 (N=512: only 128 blocks at 256sq) stay
//      on gemm_p2; x_proj/dt_proj unchanged.
// R17: branch-free softplus. R16: 2-way bijection p2, counted vmcnt.
// R13: conv_silu rolling window; gld_lds width=16. R12: scan fast-path exp.

#define DEV __device__ __forceinline__

typedef unsigned short u16;
typedef u16    u16x8  __attribute__((ext_vector_type(8)));
typedef __bf16 bf16x8 __attribute__((ext_vector_type(8)));
typedef float  f32x4  __attribute__((ext_vector_type(4)));

static constexpr int L_SEQ = 16384;
static constexpr int LC    = 64;    // scan chunk length
static constexpr int NCH   = 256;   // number of chunks

DEV u16 f2b(float x){
  union { float f; unsigned u; } c; c.f = x;
  unsigned u = c.u;
  return (u16)((u + 0x7fffu + ((u >> 16) & 1u)) >> 16);   // RNE
}
DEV float b2f(u16 h){
  union { unsigned u; float f; } c; c.u = ((unsigned)h) << 16;
  return c.f;
}
DEV int ldix(const void* p, int l, bool is64){
  return is64 ? (int)((const long long*)p)[l] : ((const int*)p)[l];
}
DEV float siluf(float x){ return x / (1.f + __expf(-x)); }
// branch-free: log(1+e^x) = max(x,0) + log(1+e^-|x|)
DEV float softplusf(float x){
  return fmaxf(x, 0.f) + __logf(1.f + __expf(-fabsf(x)));
}
DEV float geluf(float x){ return 0.5f * x * (1.f + erff(x * 0.70710678118f)); }

// direct global->LDS async copy, 16B per lane (dest = wave-uniform base +
// lane*16 -- holds for linear tid*16 layouts)
DEV void gld_lds16(const u16* g, u16* l){
  __builtin_amdgcn_global_load_lds(
      (const __attribute__((address_space(1))) unsigned*)g,
      (__attribute__((address_space(3))) unsigned*)l, 16, 0, 0);
}

// r^(s+1) for s=0..15 via log-depth power chain
DEV void pow16(float r, float* a){
  float r2 = r * r, r4 = r2 * r2, r8 = r4 * r4;
  a[0] = r;        a[1] = r2;       a[2] = r2 * r;    a[3] = r4;
  a[4] = r4 * r;   a[5] = r4 * r2;  a[6] = r4 * a[2]; a[7] = r8;
  a[8] = r8 * r;   a[9] = r8 * r2;  a[10] = r8 * a[2]; a[11] = r8 * r4;
  a[12] = r8 * a[4]; a[13] = r8 * a[5]; a[14] = r8 * a[6]; a[15] = r8 * r8;
}

// ---------------------------------------------------------------------------
__global__ __launch_bounds__(256) void fill_k(float* out, float v, unsigned n){
  unsigned i = blockIdx.x * 256 + threadIdx.x;
  if (i < n) out[i] = v;
}

__global__ void detect_k(const int* ord32, int* flag){
  flag[0] = (ord32[1] == 0 && ord32[3] == 0 && ord32[5] == 0) ? 1 : 0;
  flag[1] = 0;
}

// verify A_log[d][s] == A_log[d][0] + log(s+1)
__global__ __launch_bounds__(256) void checkA_k(const float* __restrict__ alog,
                                                int* flag){
  int i = blockIdx.x * 256 + threadIdx.x;
  int s = i & 15;
  float v = alog[i];
  float base = alog[i - s];
  if (fabsf(v - (base + __logf((float)(s + 1)))) > 1e-4f) atomicOr(flag + 1, 1);
}

struct NT4 { const float* src[4]; unsigned off[5]; };
__global__ __launch_bounds__(256) void normw_k(NT4 t, u16* dst){
  unsigned i = blockIdx.x * 256 + threadIdx.x;
  if (i >= t.off[4]) return;
  int s = 0;
  #pragma unroll
  for (int k = 1; k <= 3; k++) s += (i >= t.off[k]) ? 1 : 0;
  dst[i] = f2b(t.src[s][i - t.off[s]]);
}

// transpose-convert: out[n*K + k] = f2b(in[k*N + n])
__global__ __launch_bounds__(256) void convT_kernel(const float* __restrict__ in,
                                                    u16* __restrict__ out, int K, int N){
  __shared__ float t[32][33];
  int k0 = blockIdx.x * 32, n0 = blockIdx.y * 32;
  int tx = threadIdx.x & 31, ty = threadIdx.x >> 5;
  #pragma unroll
  for (int i = 0; i < 32; i += 8)
    t[ty + i][tx] = in[(size_t)(k0 + ty + i) * N + n0 + tx];
  __syncthreads();
  #pragma unroll
  for (int i = 0; i < 32; i += 8)
    out[(size_t)(n0 + ty + i) * K + k0 + tx] = f2b(t[tx][ty + i]);
}

// ---------------------------------------------------------------------------
// layernorms (C=512, one block/row, LDS tree)
// ---------------------------------------------------------------------------
__global__ __launch_bounds__(256) void gather_ln1(const float* __restrict__ feat,
    const void* order, const float* __restrict__ w, const float* __restrict__ b,
    const int* flag, u16* __restrict__ x1b){
  __shared__ float rs_[256], rq_[256];
  const bool is64 = flag[0] != 0;
  int l = blockIdx.x, tid = threadIdx.x;
  int src = ldix(order, l, is64);
  float v0 = feat[(size_t)src * 512 + tid];
  float v1 = feat[(size_t)src * 512 + tid + 256];
  rs_[tid] = v0 + v1; rq_[tid] = v0 * v0 + v1 * v1;
  __syncthreads();
  for (int o = 128; o; o >>= 1){
    if (tid < o){ rs_[tid] += rs_[tid + o]; rq_[tid] += rq_[tid + o]; }
    __syncthreads();
  }
  float mu = rs_[0] * (1.f / 512.f);
  float var = rq_[0] * (1.f / 512.f) - mu * mu;
  float rstd = rsqrtf(var + 1e-5f);
  x1b[(size_t)l * 512 + tid]       = f2b((v0 - mu) * rstd * w[tid]       + b[tid]);
  x1b[(size_t)l * 512 + tid + 256] = f2b((v1 - mu) * rstd * w[tid + 256] + b[tid + 256]);
}

__global__ __launch_bounds__(256) void ln2_kernel(const float* __restrict__ x,
    const float* __restrict__ w, const float* __restrict__ b, u16* __restrict__ h2b){
  __shared__ float rs_[256], rq_[256];
  int l = blockIdx.x, tid = threadIdx.x;
  float v0 = x[(size_t)l * 512 + tid];
  float v1 = x[(size_t)l * 512 + tid + 256];
  rs_[tid] = v0 + v1; rq_[tid] = v0 * v0 + v1 * v1;
  __syncthreads();
  for (int o = 128; o; o >>= 1){
    if (tid < o){ rs_[tid] += rs_[tid + o]; rq_[tid] += rq_[tid + o]; }
    __syncthreads();
  }
  float mu = rs_[0] * (1.f / 512.f);
  float var = rq_[0] * (1.f / 512.f) - mu * mu;
  float rstd = rsqrtf(var + 1e-5f);
  h2b[(size_t)l * 512 + tid]       = f2b((v0 - mu) * rstd * w[tid]       + b[tid]);
  h2b[(size_t)l * 512 + tid + 256] = f2b((v1 - mu) * rstd * w[tid + 256] + b[tid + 256]);
}

// ---------------------------------------------------------------------------
// depthwise causal conv (k=4) + silu -- vectorized rolling window.
// ---------------------------------------------------------------------------
__global__ __launch_bounds__(256) void conv_silu(const u16* __restrict__ xm,
    const float* __restrict__ cw, const float* __restrict__ cb, u16* __restrict__ xcb){
  constexpr int TT = 8;
  const int tid = threadIdx.x;
  const int d0 = (tid & 127) * 8;
  const int t0 = (blockIdx.x * 2 + (tid >> 7)) * TT;

  float wk[4][8], bias[8];
  #pragma unroll
  for (int j = 0; j < 8; j++) bias[j] = cb[d0 + j];
  #pragma unroll
  for (int j = 0; j < 8; j++){
    f32x4 v = *(const f32x4*)(cw + (d0 + j) * 4);
    wk[0][j] = v[0]; wk[1][j] = v[1]; wk[2][j] = v[2]; wk[3][j] = v[3];
  }

  float win[3][8];
  #pragma unroll
  for (int k = 0; k < 3; k++){
    int tt = t0 - 3 + k;
    if (tt >= 0){
      u16x8 v = *(const u16x8*)(xm + (size_t)tt * 1024 + d0);
      #pragma unroll
      for (int j = 0; j < 8; j++) win[k][j] = b2f(v[j]);
    } else {
      #pragma unroll
      for (int j = 0; j < 8; j++) win[k][j] = 0.f;
    }
  }

  #pragma unroll
  for (int t = 0; t < TT; t++){
    u16x8 v = *(const u16x8*)(xm + (size_t)(t0 + t) * 1024 + d0);
    u16x8 o;
    float cu[8];
    #pragma unroll
    for (int j = 0; j < 8; j++){
      cu[j] = b2f(v[j]);
      float acc = bias[j] + win[0][j] * wk[0][j] + win[1][j] * wk[1][j]
                + win[2][j] * wk[2][j] + cu[j] * wk[3][j];
      o[j] = f2b(siluf(acc));
    }
    *(u16x8*)(xcb + (size_t)(t0 + t) * 1024 + d0) = o;
    #pragma unroll
    for (int j = 0; j < 8; j++){
      win[0][j] = win[1][j]; win[1][j] = win[2][j]; win[2][j] = cu[j];
    }
  }
}

// ---------------------------------------------------------------------------
// bf16 MFMA GEMM, C = A (MxK, lda) * B^T (NxK, ldb), fused epilogues.
// ---------------------------------------------------------------------------
enum { M_BF16 = 0, M_INPROJ = 1, M_DT = 2, M_RES = 3, M_GELU = 4, M_FFN2 = 5 };

template<int MODE>
DEV void gemm_epilogue(float v, int m, int n, int N,
    float* __restrict__ outf, u16* __restrict__ outb, u16* __restrict__ outb2,
    const float* __restrict__ auxf, const float* __restrict__ auxw,
    const void* ordv, bool is64){
  size_t o = (size_t)m * N + n;
  if constexpr (MODE == M_BF16){
    outb[o] = f2b(v);
  } else if constexpr (MODE == M_INPROJ){
    if (n < 1024) outb [(size_t)m * 1024 + n]          = f2b(v);
    else          outb2[(size_t)m * 1024 + (n - 1024)] = f2b(siluf(v));
  } else if constexpr (MODE == M_DT){
    outb[o] = f2b(softplusf(v + auxw[n]));
  } else if constexpr (MODE == M_RES){
    int src = ldix(ordv, m, is64);
    outf[o] = v + auxw[(size_t)src * 512 + n];   // + feat[order[m]]
  } else if constexpr (MODE == M_GELU){
    outb[o] = f2b(geluf(v + auxw[n]));
  } else { // M_FFN2: + bias + residual -> fp32 (serialized order)
    outf[o] = v + auxw[n] + auxf[o];
  }
}

// ---------------------------------------------------------------------------
// R20: 8-phase 256x256 GEMM (m201 template). Requires K % 128 == 0,
// M % 256 == 0, N % 256 == 0. See file header for the stage-schedule ledger.
// ---------------------------------------------------------------------------
#define PH8(BUF, MH, KS, LOADB, ...)                                        \
  do {                                                                      \
    bf16x8 af_[4];                                                          \
    _Pragma("unroll")                                                       \
    for (int mi = 0; mi < 4; mi++){                                         \
      int R = wr * 128 + (MH) * 64 + mi * 16 + rr;                          \
      int slot = ((KS) * 4 + qc) ^ (R & 7);                                 \
      af_[mi] = *(const bf16x8*)(&sA[BUF][R * 64 + slot * 8]);              \
    }                                                                       \
    if constexpr (LOADB){                                                   \
      _Pragma("unroll")                                                     \
      for (int nj = 0; nj < 4; nj++){                                       \
        int R = wc * 64 + nj * 16 + rr;                                     \
        int slot = ((KS) * 4 + qc) ^ (R & 7);                               \
        bfr[KS][nj] = *(const bf16x8*)(&sB[BUF][R * 64 + slot * 8]);        \
      }                                                                     \
    }                                                                       \
    __VA_ARGS__;                                                            \
    __builtin_amdgcn_s_barrier();                                           \
    asm volatile("s_waitcnt lgkmcnt(0)" ::: "memory");                      \
    __builtin_amdgcn_sched_barrier(0);                                      \
    __builtin_amdgcn_s_setprio(1);                                          \
    _Pragma("unroll")                                                       \
    for (int mi = 0; mi < 4; mi++)                                          \
      _Pragma("unroll")                                                     \
      for (int nj = 0; nj < 4; nj++)                                        \
        acc[(MH) * 4 + mi][nj] = __builtin_amdgcn_mfma_f32_16x16x32_bf16(   \
            af_[mi], bfr[KS][nj], acc[(MH) * 4 + mi][nj], 0, 0, 0);         \
    __builtin_amdgcn_s_setprio(0);                                          \
    __builtin_amdgcn_s_barrier();                                           \
  } while (0)

template<int MODE>
__global__ __launch_bounds__(512, 2) void gemm_8ph(
    const u16* __restrict__ A, const u16* __restrict__ B,
    int N, int K, int lda, int ldb,
    float* __restrict__ outf, u16* __restrict__ outb, u16* __restrict__ outb2,
    const float* __restrict__ auxf, const float* __restrict__ auxw,
    const void* ordv, const int* flag){
  __shared__ __align__(16) u16 sA[2][256 * 64];   // [buf][row*64 + slot*8]
  __shared__ __align__(16) u16 sB[2][256 * 64];
  const int tid  = threadIdx.x;                   // 0..511
  const int wave = tid >> 6, lane = tid & 63;
  const int wr = wave >> 2, wc = wave & 3;        // 2 x 4 wave grid
  const int m0 = blockIdx.x * 256, n0 = blockIdx.y * 256;
  const int rr = lane & 15, qc = lane >> 4;

  f32x4  acc[8][4] = {};
  bf16x8 bfr[2][4];                               // [ks][nj], cached over mh

  const int srow = tid >> 3, ssub = tid & 7;
  // stage one 8KB unit (64-row band): linear LDS dest (tid*16B), source
  // chunk inverse-swizzled cg = sub ^ (row&7); read applies the same XOR.
  auto stA = [&](int buf, int band, int kt){
    int row = band * 64 + srow;
    int cg = ssub ^ (row & 7);
    gld_lds16(A + (size_t)(m0 + row) * lda + kt * 64 + cg * 8,
              &sA[buf][band * 4096 + tid * 8]);
  };
  auto stB = [&](int buf, int band, int kt){
    int row = band * 64 + srow;
    int cg = ssub ^ (row & 7);
    gld_lds16(B + (size_t)(n0 + row) * ldb + kt * 64 + cg * 8,
              &sB[buf][band * 4096 + tid * 8]);
  };

  const int nst = K / 64, its = nst / 2;

  // prologue: buf0 <- Kt0 (all 8 units), buf1 <- Kt1 (B0-3, A0, A2);
  // buf1's A1,A3 are staged by ph1 of iteration 0. vmcnt(6): buf0's 8 landed.
  stA(0,0,0); stA(0,1,0); stA(0,2,0); stA(0,3,0);
  stB(0,0,0); stB(0,1,0); stB(0,2,0); stB(0,3,0);
  stB(1,0,1); stB(1,1,1); stB(1,2,1); stB(1,3,1);
  stA(1,0,1); stA(1,2,1);
  asm volatile("s_waitcnt vmcnt(6)" ::: "memory");
  __builtin_amdgcn_s_barrier();

  for (int it = 0; it < its; ++it){
    const int k2  = 2 * it + 1;
    const int kn1 = 2 * it + 2, kn2 = 2 * it + 3;
    const bool pre = (it + 1 < its);
    // ph1: buf0 (mh0,ks0); stage buf1 A1,A3 <- Kt(2i+1)  [read ph7-8 this it]
    PH8(0, 0, 0, true,  stA(1,1,k2); stA(1,3,k2) );
    // ph2: buf0 (mh0,ks1)
    PH8(0, 0, 1, true,  ((void)0) );
    // ph3: buf0 (mh1,ks0); stage buf0 B0,B1 <- Kt(2i+2)
    PH8(0, 1, 0, false, if (pre){ stB(0,0,kn1); stB(0,1,kn1); } );
    // ph4: buf0 (mh1,ks1); stage buf0 B2,B3,A0; vmcnt(5) covers <=ph1 stages
    // (prev ph7,8 + this ph1 = buf1's data for ph5-8). Final iter: no ph3/4
    // stages issued -> counted value would not cover ph1; drain instead.
    PH8(0, 1, 1, false,
        if (pre){ stB(0,2,kn1); stB(0,3,kn1); stA(0,0,kn1);
                  asm volatile("s_waitcnt vmcnt(5)" ::: "memory"); }
        else    { asm volatile("s_waitcnt vmcnt(0)" ::: "memory"); } );
    // ph5: buf1 (mh0,ks0); stage buf0 A2,A1,A3 <- Kt(2i+2)
    PH8(1, 0, 0, true,  if (pre){ stA(0,2,kn1); stA(0,1,kn1); stA(0,3,kn1); } );
    // ph6: buf1 (mh0,ks1)
    PH8(1, 0, 1, true,  ((void)0) );
    // ph7: buf1 (mh1,ks0); stage buf1 B0,B1,B2 <- Kt(2i+3)
    PH8(1, 1, 0, false, if (pre){ stB(1,0,kn2); stB(1,1,kn2); stB(1,2,kn2); } );
    // ph8: buf1 (mh1,ks1); stage buf1 B3,A0,A2; vmcnt(6) covers <=ph5 stages
    // (buf0's full next K-tile). Final iter: nothing to cover.
    PH8(1, 1, 1, false,
        if (pre){ stB(1,3,kn2); stA(1,0,kn2); stA(1,2,kn2);
                  asm volatile("s_waitcnt vmcnt(6)" ::: "memory"); } );
  }

  const bool is64 = flag ? (flag[0] != 0) : false;
  // D layout: col(N) = lane&15, row(M) = (lane>>4)*4 + r   [m89-verified]
  #pragma unroll
  for (int mi = 0; mi < 8; mi++)
    #pragma unroll
    for (int nj = 0; nj < 4; nj++)
      #pragma unroll
      for (int r = 0; r < 4; r++){
        int m = m0 + wr * 128 + mi * 16 + ((lane >> 4) << 2) + r;
        int n = n0 + wc * 64 + nj * 16 + (lane & 15);
        gemm_epilogue<MODE>(acc[mi][nj][r], m, n, N, outf, outb, outb2,
                            auxf, auxw, ordv, is64);
      }
}

// depth-2 pipelined GEMM (R17 schedule; geometry-parametric). Kept for
// out_proj/FFN2 (N=512) and x_proj. 3 LDS buffers, counted vmcnt, 2-way
// LDS bijection (involution both-sides). Requires K % 32 == 0.
template<int BM, int BN, int WM, int WN, int MODE>
__global__ __launch_bounds__((BM / WM) * (BN / WN) * 64) void gemm_p2(
    const u16* __restrict__ A, const u16* __restrict__ B,
    int N, int K, int lda, int ldb,
    float* __restrict__ outf, u16* __restrict__ outb, u16* __restrict__ outb2,
    const float* __restrict__ auxf, const float* __restrict__ auxw,
    const void* ordv, const int* flag){
  constexpr int BK = 32;
  constexpr int MI = WM / 16, NI = WN / 16;
  constexpr int WCOLS = BN / WN;
  constexpr int THREADS = (BM / WM) * (BN / WN) * 64;
  constexpr int NA = BM * BK / (THREADS * 8);
  constexpr int NB = BN * BK / (THREADS * 8);
  constexpr int LPS = NA + NB;
  static_assert(LPS == 2 || LPS == 3 || LPS == 4, "vmcnt literals");
  __shared__ __align__(16) u16 sA[3][BM * BK];
  __shared__ __align__(16) u16 sB[3][BN * BK];
  const int tid  = threadIdx.x;
  const int wave = tid >> 6, lane = tid & 63;
  const int wr = wave / WCOLS, wc = wave % WCOLS;
  const int m0 = blockIdx.x * BM, n0 = blockIdx.y * BN;
  const int rr = lane & 15;
  const int qc = lane >> 4;

  f32x4 acc[MI][NI] = {};

  auto stage = [&](int buf, int k0){
    #pragma unroll
    for (int i = 0; i < NA; i++){
      int idx = tid + i * THREADS;
      int row = idx >> 2, sub = idx & 3;
      int cg = (sub - (row >> 1)) & 3;
      gld_lds16(A + (size_t)(m0 + row) * lda + k0 + cg * 8, &sA[buf][idx * 8]);
    }
    #pragma unroll
    for (int i = 0; i < NB; i++){
      int idx = tid + i * THREADS;
      int row = idx >> 2, sub = idx & 3;
      int cg = (sub - (row >> 1)) & 3;
      gld_lds16(B + (size_t)(n0 + row) * ldb + k0 + cg * 8, &sB[buf][idx * 8]);
    }
  };

  const int nst = K / BK;
  stage(0, 0);
  if (nst > 1) stage(1, BK);
  for (int st = 0; st < nst; st++){
    if (st + 2 < nst) stage((st + 2) % 3, (st + 2) * BK);
    const int nf = (st + 2 < nst) ? 2 : ((st + 1 < nst) ? 1 : 0);
    if (nf == 2){
      if constexpr (LPS == 4)      asm volatile("s_waitcnt vmcnt(8)" ::: "memory");
      else if constexpr (LPS == 3) asm volatile("s_waitcnt vmcnt(6)" ::: "memory");
      else                         asm volatile("s_waitcnt vmcnt(4)" ::: "memory");
    } else if (nf == 1){
      if constexpr (LPS == 4)      asm volatile("s_waitcnt vmcnt(4)" ::: "memory");
      else if constexpr (LPS == 3) asm volatile("s_waitcnt vmcnt(3)" ::: "memory");
      else                         asm volatile("s_waitcnt vmcnt(2)" ::: "memory");
    } else {
      asm volatile("s_waitcnt vmcnt(0)" ::: "memory");
    }
    __builtin_amdgcn_s_barrier();
    __builtin_amdgcn_sched_barrier(0);

    const int cur = st % 3;
    bf16x8 af[MI], bfr[NI];
    #pragma unroll
    for (int i = 0; i < MI; i++){
      int R = wr * WM + i * 16 + rr;
      int slot = (qc + (R >> 1)) & 3;
      af[i] = *(const bf16x8*)(&sA[cur][R * BK + slot * 8]);
    }
    #pragma unroll
    for (int j = 0; j < NI; j++){
      int R = wc * WN + j * 16 + rr;
      int slot = (qc + (R >> 1)) & 3;
      bfr[j] = *(const bf16x8*)(&sB[cur][R * BK + slot * 8]);
    }
    #pragma unroll
    for (int i = 0; i < MI; i++)
      #pragma unroll
      for (int j = 0; j < NI; j++)
        acc[i][j] = __builtin_amdgcn_mfma_f32_16x16x32_bf16(af[i], bfr[j], acc[i][j], 0, 0, 0);

    asm volatile("s_waitcnt lgkmcnt(0)" ::: "memory");
    __builtin_amdgcn_s_barrier();
    __builtin_amdgcn_sched_barrier(0);
  }

  const bool is64 = flag ? (flag[0] != 0) : false;
  #pragma unroll
  for (int i = 0; i < MI; i++)
    #pragma unroll
    for (int j = 0; j < NI; j++)
      #pragma unroll
      for (int r = 0; r < 4; r++){
        int m = m0 + wr * WM + i * 16 + ((lane >> 4) << 2) + r;
        int n = n0 + wc * WN + j * 16 + (lane & 15);
        gemm_epilogue<MODE>(acc[i][j][r], m, n, N, outf, outb, outb2,
                            auxf, auxw, ordv, is64);
      }
}

// Legacy BK=32 single-buffer variant (dt_proj, K=32).
template<int BM, int BN, int WM, int WN, int MODE>
__global__ __launch_bounds__(256) void gemm_bt(
    const u16* __restrict__ A, const u16* __restrict__ B,
    int N, int K, int lda, int ldb,
    float* __restrict__ outf, u16* __restrict__ outb, u16* __restrict__ outb2,
    const float* __restrict__ auxf, const float* __restrict__ auxw,
    const void* ordv, const int* flag){
  constexpr int BK = 32;
  constexpr int MI = WM / 16, NI = WN / 16;
  constexpr int WCOLS = BN / WN;
  constexpr int NA = BM * 4 / 256;
  constexpr int NB = BN * 4 / 256;
  __shared__ __align__(16) u16 sA[BM * BK];
  __shared__ __align__(16) u16 sB[BN * BK];
  const int tid  = threadIdx.x;
  const int wave = tid >> 6, lane = tid & 63;
  const int wr = wave / WCOLS, wc = wave % WCOLS;
  const int m0 = blockIdx.x * BM, n0 = blockIdx.y * BN;
  const int rr = lane & 15;
  const int qk = (lane >> 4) * 8;

  f32x4 acc[MI][NI] = {};

  for (int k0 = 0; k0 < K; k0 += BK){
    #pragma unroll
    for (int i = 0; i < NA; i++){
      int idx = tid + i * 256;
      int r = idx >> 2, c = (idx & 3) * 8;
      gld_lds16(A + (size_t)(m0 + r) * lda + k0 + c, sA + (size_t)idx * 8);
    }
    #pragma unroll
    for (int i = 0; i < NB; i++){
      int idx = tid + i * 256;
      int r = idx >> 2, c = (idx & 3) * 8;
      gld_lds16(B + (size_t)(n0 + r) * ldb + k0 + c, sB + (size_t)idx * 8);
    }
    __syncthreads();

    bf16x8 af[MI], bfr[NI];
    #pragma unroll
    for (int i = 0; i < MI; i++)
      af[i] = *(const bf16x8*)(sA + (wr * WM + i * 16 + rr) * BK + qk);
    #pragma unroll
    for (int j = 0; j < NI; j++)
      bfr[j] = *(const bf16x8*)(sB + (wc * WN + j * 16 + rr) * BK + qk);
    #pragma unroll
    for (int i = 0; i < MI; i++)
      #pragma unroll
      for (int j = 0; j < NI; j++)
        acc[i][j] = __builtin_amdgcn_mfma_f32_16x16x32_bf16(af[i], bfr[j], acc[i][j], 0, 0, 0);
    __syncthreads();
  }

  const bool is64 = flag ? (flag[0] != 0) : false;
  #pragma unroll
  for (int i = 0; i < MI; i++)
    #pragma unroll
    for (int j = 0; j < NI; j++)
      #pragma unroll
      for (int r = 0; r < 4; r++){
        int m = m0 + wr * WM + i * 16 + ((lane >> 4) << 2) + r;
        int n = n0 + wc * WN + j * 16 + (lane & 15);
        gemm_epilogue<MODE>(acc[i][j][r], m, n, N, outf, outb, outb2,
                            auxf, auxw, ordv, is64);
      }
}

// ---------------------------------------------------------------------------
// chunked selective scan (fp32 state; chP/chH bf16, layout [chunk][s][d])
// ---------------------------------------------------------------------------
__global__ __launch_bounds__(256) void scan_pass1(const u16* __restrict__ dt,
    const u16* __restrict__ xc, const u16* __restrict__ dbc,
    const float* __restrict__ alog, const int* __restrict__ flag,
    u16* __restrict__ chP, u16* __restrict__ chH){
  __shared__ float sB[LC * 16];
  const int chunk = blockIdx.x;
  const int d = blockIdx.y * 256 + threadIdx.x;
  const int t0 = chunk * LC;
  for (int i = threadIdx.x; i < LC * 16; i += 256){
    int t = i >> 4, s = i & 15;
    sB[i] = b2f(dbc[(size_t)(t0 + t) * 64 + 32 + s]);
  }
  __syncthreads();
  float h[16];
  #pragma unroll
  for (int s = 0; s < 16; s++) h[s] = 0.f;
  float P[16];
  const bool fastA = (flag[1] == 0);
  if (fastA){
    const float a0 = -__expf(alog[(size_t)d * 16]);
    float R = 1.f;
    for (int t = 0; t < LC; t++){
      float dtv = b2f(dt[(size_t)(t0 + t) * 1024 + d]);
      float xv  = b2f(xc[(size_t)(t0 + t) * 1024 + d]);
      float dtx = dtv * xv;
      float r = __expf(dtv * a0);
      R *= r;
      float a_[16];
      pow16(r, a_);
      #pragma unroll
      for (int s = 0; s < 16; s++)
        h[s] = a_[s] * h[s] + dtx * sB[t * 16 + s];
    }
    pow16(R, P);
  } else {
    float A[16];
    #pragma unroll
    for (int s = 0; s < 16; s++){
      A[s] = -__expf(alog[(size_t)d * 16 + s]);
      P[s] = 1.f;
    }
    for (int t = 0; t < LC; t++){
      float dtv = b2f(dt[(size_t)(t0 + t) * 1024 + d]);
      float xv  = b2f(xc[(size_t)(t0 + t) * 1024 + d]);
      float dtx = dtv * xv;
      #pragma unroll
      for (int s = 0; s < 16; s++){
        float a = __expf(dtv * A[s]);
        P[s] *= a;
        h[s] = a * h[s] + dtx * sB[t * 16 + s];
      }
    }
  }
  #pragma unroll
  for (int s = 0; s < 16; s++){
    chP[((size_t)chunk * 16 + s) * 1024 + d] = f2b(P[s]);
    chH[((size_t)chunk * 16 + s) * 1024 + d] = f2b(h[s]);
  }
}

// hin may alias chP: window loads 8 ahead into regs before storing.
__global__ __launch_bounds__(64) void carry_scan(const u16* chP, const u16* chH,
                                                 u16* hin){
  int id = blockIdx.x * 64 + threadIdx.x;
  float h = 0.f;
  for (int k = 0; k < NCH; k += 8){
    float P[8], E[8];
    #pragma unroll
    for (int j = 0; j < 8; j++){
      P[j] = b2f(chP[(size_t)(k + j) * 16384 + id]);
      E[j] = b2f(chH[(size_t)(k + j) * 16384 + id]);
    }
    #pragma unroll
    for (int j = 0; j < 8; j++){
      hin[(size_t)(k + j) * 16384 + id] = f2b(h);
      h = P[j] * h + E[j];
    }
  }
}

__global__ __launch_bounds__(256) void scan_pass3(const u16* __restrict__ dt,
    const u16* xc, const u16* __restrict__ dbc,
    const float* __restrict__ alog, const int* __restrict__ flag,
    const u16* __restrict__ hin,
    const float* __restrict__ dskip, const u16* __restrict__ zsil, u16* yb){
  __shared__ float sBC[LC * 32];
  const int chunk = blockIdx.x;
  const int d = blockIdx.y * 256 + threadIdx.x;
  const int t0 = chunk * LC;
  for (int i = threadIdx.x; i < LC * 32; i += 256){
    int t = i >> 5, c = i & 31;
    sBC[i] = b2f(dbc[(size_t)(t0 + t) * 64 + 32 + c]);
  }
  __syncthreads();
  float h[16];
  #pragma unroll
  for (int s = 0; s < 16; s++)
    h[s] = b2f(hin[((size_t)chunk * 16 + s) * 1024 + d]);
  const float Dv = dskip[d];
  const bool fastA = (flag[1] == 0);
  if (fastA){
    const float a0 = -__expf(alog[(size_t)d * 16]);
    for (int t = 0; t < LC; t++){
      float dtv = b2f(dt[(size_t)(t0 + t) * 1024 + d]);
      float xv  = b2f(xc[(size_t)(t0 + t) * 1024 + d]);
      float dtx = dtv * xv;
      float r = __expf(dtv * a0);
      float a_[16];
      pow16(r, a_);
      float y = 0.f;
      #pragma unroll
      for (int s = 0; s < 16; s++){
        h[s] = a_[s] * h[s] + dtx * sBC[t * 32 + s];
        y += h[s] * sBC[t * 32 + 16 + s];
      }
      float rv = (y + xv * Dv) * b2f(zsil[(size_t)(t0 + t) * 1024 + d]);
      yb[(size_t)(t0 + t) * 1024 + d] = f2b(rv);
    }
  } else {
    float A[16];
    #pragma unroll
    for (int s = 0; s < 16; s++) A[s] = -__expf(alog[(size_t)d * 16 + s]);
    for (int t = 0; t < LC; t++){
      float dtv = b2f(dt[(size_t)(t0 + t) * 1024 + d]);
      float xv  = b2f(xc[(size_t)(t0 + t) * 1024 + d]);
      float dtx = dtv * xv;
      float y = 0.f;
      #pragma unroll
      for (int s = 0; s < 16; s++){
        float a = __expf(dtv * A[s]);
        h[s] = a * h[s] + dtx * sBC[t * 32 + s];
        y += h[s] * sBC[t * 32 + 16 + s];
      }
      float rv = (y + xv * Dv) * b2f(zsil[(size_t)(t0 + t) * 1024 + d]);
      yb[(size_t)(t0 + t) * 1024 + d] = f2b(rv);
    }
  }
}

// final: out[i] = xfin[inverse[i]] — fp32, sole d_out writer.
__global__ __launch_bounds__(256) void final_gather(const float* __restrict__ xfin,
    const void* inv, const int* flag, float* __restrict__ out){
  const bool is64 = flag[0] != 0;
  int i = blockIdx.x, tid = threadIdx.x;
  int src = ldix(inv, i, is64);
  out[(size_t)i * 512 + tid]       = xfin[(size_t)src * 512 + tid];
  out[(size_t)i * 512 + tid + 256] = xfin[(size_t)src * 512 + tid + 256];
}

// ---------------------------------------------------------------------------
extern "C" void kernel_launch(void* const* d_in, const int* in_sizes, int n_in,
                              void* d_out, int out_size, void* d_ws, size_t ws_size,
                              hipStream_t stream){
  float* out = (float*)d_out;
  char* w = (char*)d_ws;

  constexpr size_t OFF_W1T  = 3342336;
  constexpr size_t OFF_W2T  = OFF_W1T + 1048576;
  constexpr size_t OFF_FLAG = OFF_W2T + 1048576;
  constexpr size_t OFF_XMB  = 5439744;               // 32MiB xmb / dtb / x(fp32)
  constexpr size_t OFF_ZSIL = OFF_XMB  + 33554432;   // 32MiB zsil / midb
  constexpr size_t OFF_XCB  = OFF_ZSIL + 33554432;   // 32MiB xcb / yb / xfin(fp32)
  constexpr size_t OFF_X1B  = OFF_XCB  + 33554432;   // 16MiB x1b / h2b / chP+chH
  constexpr size_t OFF_DBC  = OFF_X1B  + 16777216;   //  2MiB
  constexpr size_t OFF_CHP  = OFF_X1B;               //  8MiB (over dead x1b)
  constexpr size_t OFF_CHH  = OFF_X1B  + 8388608;    //  8MiB
  constexpr size_t WS_NEED  = OFF_DBC  + 2097152;

  int code = 0;
  static const int want[20] = {8388608,16384,16384,512,512,1048576,4096,1024,
                               65536,32768,1024,16384,1024,524288,512,512,
                               524288,1024,524288,512};
  if (n_in != 20) code = 1000;
  else {
    for (int i = 0; i < 20 && !code; i++)
      if (in_sizes[i] != want[i]) code = 2000 + i * 50;
    if (!code && out_size != 8388608) code = 3000;
    if (!code && ws_size < WS_NEED)   code = 4000;
  }
  if (code){
    unsigned n = (unsigned)(out_size > 0 ? out_size : 1);
    fill_k<<<(n + 255) / 256, 256, 0, stream>>>(out, (float)code, n);
    return;
  }

  u16*   w1tb = (u16*)(w + OFF_W1T);
  u16*   w2tb = (u16*)(w + OFF_W2T);
  int*   flag = (int*)(w + OFF_FLAG);
  u16*   xmb  = (u16*)(w + OFF_XMB);
  u16*   zsil = (u16*)(w + OFF_ZSIL);
  u16*   xcb  = (u16*)(w + OFF_XCB);
  u16*   x1b  = (u16*)(w + OFF_X1B);
  u16*   dbcb = (u16*)(w + OFF_DBC);
  u16*   chP  = (u16*)(w + OFF_CHP);
  u16*   chH  = (u16*)(w + OFF_CHH);
  float* x    = (float*)(w + OFF_XMB);
  float* xfin = (float*)(w + OFF_XCB);
  u16* dtb  = xmb;
  u16* yb   = xcb;
  u16* midb = zsil;
  u16* h2b  = x1b;
  u16* hin  = chP;

  u16* nb = (u16*)w;
  u16* inpjn  = nb;
  u16* xpjn   = nb + 1048576;
  u16* dtpjn  = nb + 1114112;
  u16* outpjn = nb + 1146880;
  NT4 t;
  t.src[0] = (const float*)d_in[5];  t.src[1] = (const float*)d_in[8];
  t.src[2] = (const float*)d_in[9];  t.src[3] = (const float*)d_in[13];
  t.off[0] = 0; t.off[1] = 1048576; t.off[2] = 1114112; t.off[3] = 1146880; t.off[4] = 1671168;

  detect_k<<<1, 1, 0, stream>>>((const int*)d_in[1], flag);
  checkA_k<<<64, 256, 0, stream>>>((const float*)d_in[11], flag);
  normw_k<<<(1671168 + 255) / 256, 256, 0, stream>>>(t, nb);
  convT_kernel<<<dim3(16, 32), 256, 0, stream>>>((const float*)d_in[16], w1tb, 512, 1024);
  convT_kernel<<<dim3(32, 16), 256, 0, stream>>>((const float*)d_in[18], w2tb, 1024, 512);

  // 1. gather + LN1
  gather_ln1<<<L_SEQ, 256, 0, stream>>>((const float*)d_in[0], d_in[1],
      (const float*)d_in[3], (const float*)d_in[4], flag, x1b);

  // 2. in_proj -> xmb | silu(z)   (K=512: 8-phase, 512 blocks)
  gemm_8ph<M_INPROJ><<<dim3(64,8),512,0,stream>>>(
      x1b, inpjn, 2048, 512, 512, 512, nullptr, xmb, zsil, nullptr, nullptr, nullptr, nullptr);

  // 3. conv + silu
  conv_silu<<<1024, 256, 0, stream>>>(xmb,
      (const float*)d_in[6], (const float*)d_in[7], xcb);

  // 4. x_proj -> dbcb   (K=1024; 64x64 p2)
  gemm_p2<64,64,16,64,M_BF16><<<dim3(256,1),256,0,stream>>>(
      xcb, xpjn, 64, 1024, 1024, 1024, nullptr, dbcb, nullptr, nullptr, nullptr, nullptr, nullptr);

  // 5. dt_proj + softplus -> dtb  (K=32: legacy)
  gemm_bt<128,128,64,64,M_DT><<<dim3(128,8),256,0,stream>>>(
      dbcb, dtpjn, 1024, 32, 64, 32, nullptr, dtb, nullptr, nullptr,
      (const float*)d_in[10], nullptr, nullptr);

  // 6. chunked scan
  scan_pass1<<<dim3(NCH,4),256,0,stream>>>(dtb, xcb, dbcb,
      (const float*)d_in[11], flag, chP, chH);
  carry_scan<<<256,64,0,stream>>>(chP, chH, hin);
  scan_pass3<<<dim3(NCH,4),256,0,stream>>>(dtb, xcb, dbcb,
      (const float*)d_in[11], flag, hin, (const float*)d_in[12], zsil, yb);

  // 7. out_proj + residual -> x (fp32)  (K=1024; 256x128 p2)
  gemm_p2<256,128,64,64,M_RES><<<dim3(64,4),512,0,stream>>>(
      yb, outpjn, 512, 1024, 1024, 1024, x, nullptr, nullptr, nullptr,
      (const float*)d_in[0], d_in[1], flag);

  // 8. LN2 -> h2b
  ln2_kernel<<<L_SEQ,256,0,stream>>>(x, (const float*)d_in[14], (const float*)d_in[15], h2b);

  // 9. FFN1 + gelu -> midb  (K=512: 8-phase, 256 blocks = 1/CU)
  gemm_8ph<M_GELU><<<dim3(64,4),512,0,stream>>>(
      h2b, w1tb, 1024, 512, 512, 512, nullptr, midb, nullptr, nullptr,
      (const float*)d_in[17], nullptr, nullptr);

  // 10. FFN2 + bias + residual -> xfin (fp32)  (K=1024; 256x128 p2)
  gemm_p2<256,128,64,64,M_FFN2><<<dim3(64,4),512,0,stream>>>(
      midb, w2tb, 512, 1024, 1024, 1024, xfin, nullptr, nullptr, x,
      (const float*)d_in[19], nullptr, nullptr);

  // 11. out[i] = xfin[inverse[i]]  (fp32)
  final_gather<<<L_SEQ,256,0,stream>>>(xfin, d_in[2], flag, out);
}

// Round 10
// 491.194 us; speedup vs baseline: 1.0272x; 1.0272x over previous
//
#include <hip/hip_runtime.h>

// SerializedMamba on MI355X (gfx950).
// R21: kernel-count reduction. R20 showed GEMMs at shape-limited plateau
//      (K=512: 4-iter 8ph loop, prologue+epilogue bound; FETCH ideal; both
//      2ph & 8ph ~64us). Budget moved to the tail: ~17 dispatches + mid-size
//      kernels. (a) final_gather DELETED: out[i]=xfin[inverse[i]] ==
//      out[order[m]]=xfin[m] -> FFN2 epilogue scatters to d_out directly
//      (saves kernel + gap + 64MB xfin roundtrip). (b) normw/convT1/convT2/
//      checkA fused into one prep_k (block-range dispatch; detect stays
//      separate: must zero flag[1] before checkA atomicOr). (c) float2 loads
//      + packed-u32 bf16 stores in gather_ln1/ln2; carry window 8->16.
// R20: 8-phase 256sq GEMM for in_proj/FFN1 (m201 port, refcheck'd).
// R17: branch-free softplus. R16: 2-way LDS bijection p2, counted vmcnt.
// R13: conv_silu rolling window; gld_lds width=16. R12: scan fast-path exp.

#define DEV __device__ __forceinline__

typedef unsigned short u16;
typedef u16    u16x8  __attribute__((ext_vector_type(8)));
typedef __bf16 bf16x8 __attribute__((ext_vector_type(8)));
typedef float  f32x4  __attribute__((ext_vector_type(4)));

static constexpr int L_SEQ = 16384;
static constexpr int LC    = 64;    // scan chunk length
static constexpr int NCH   = 256;   // number of chunks

DEV u16 f2b(float x){
  union { float f; unsigned u; } c; c.f = x;
  unsigned u = c.u;
  return (u16)((u + 0x7fffu + ((u >> 16) & 1u)) >> 16);   // RNE
}
DEV float b2f(u16 h){
  union { unsigned u; float f; } c; c.u = ((unsigned)h) << 16;
  return c.f;
}
DEV int ldix(const void* p, int l, bool is64){
  return is64 ? (int)((const long long*)p)[l] : ((const int*)p)[l];
}
DEV float siluf(float x){ return x / (1.f + __expf(-x)); }
// branch-free: log(1+e^x) = max(x,0) + log(1+e^-|x|)
DEV float softplusf(float x){
  return fmaxf(x, 0.f) + __logf(1.f + __expf(-fabsf(x)));
}
DEV float geluf(float x){ return 0.5f * x * (1.f + erff(x * 0.70710678118f)); }

// direct global->LDS async copy, 16B per lane (dest = wave-uniform base +
// lane*16 -- holds for linear tid*16 layouts)
DEV void gld_lds16(const u16* g, u16* l){
  __builtin_amdgcn_global_load_lds(
      (const __attribute__((address_space(1))) unsigned*)g,
      (__attribute__((address_space(3))) unsigned*)l, 16, 0, 0);
}

// r^(s+1) for s=0..15 via log-depth power chain
DEV void pow16(float r, float* a){
  float r2 = r * r, r4 = r2 * r2, r8 = r4 * r4;
  a[0] = r;        a[1] = r2;       a[2] = r2 * r;    a[3] = r4;
  a[4] = r4 * r;   a[5] = r4 * r2;  a[6] = r4 * a[2]; a[7] = r8;
  a[8] = r8 * r;   a[9] = r8 * r2;  a[10] = r8 * a[2]; a[11] = r8 * r4;
  a[12] = r8 * a[4]; a[13] = r8 * a[5]; a[14] = r8 * a[6]; a[15] = r8 * r8;
}

// ---------------------------------------------------------------------------
__global__ __launch_bounds__(256) void fill_k(float* out, float v, unsigned n){
  unsigned i = blockIdx.x * 256 + threadIdx.x;
  if (i < n) out[i] = v;
}

// flag[0]: index inputs int64; zeroes flag[1] (prep_k's checkA atomicOrs it,
// so the zero must come from an EARLIER dispatch -- intra-kernel block order
// is undefined).
__global__ void detect_k(const int* ord32, int* flag){
  flag[0] = (ord32[1] == 0 && ord32[3] == 0 && ord32[5] == 0) ? 1 : 0;
  flag[1] = 0;
}

// R21: fused preprocessing. Blocks [0,6528): normw (bf16-pack 4 B^T weights);
// [6528,7040): convT of ffn_w1 (K=512,N=1024); [7040,7552): convT of ffn_w2
// (K=1024,N=512); [7552,7616): checkA (A_log[d][s]==A_log[d][0]+log(s+1)).
struct NT4 { const float* src[4]; unsigned off[5]; };
__global__ __launch_bounds__(256) void prep_k(NT4 t, u16* dst,
    const float* w1in, u16* w1tb, const float* w2in, u16* w2tb,
    const float* alog, int* flag){
  __shared__ float ts[32][33];
  const int b = blockIdx.x;
  if (b < 6528){
    unsigned i = (unsigned)b * 256 + threadIdx.x;
    int s = 0;
    #pragma unroll
    for (int k = 1; k <= 3; k++) s += (i >= t.off[k]) ? 1 : 0;
    dst[i] = f2b(t.src[s][i - t.off[s]]);
  } else if (b < 7552){
    const float* in; u16* outp; int K, N, bx, by;
    if (b < 7040){ int id = b - 6528; in = w1in; outp = w1tb; K = 512;  N = 1024; bx = id & 15; by = id >> 4; }
    else         { int id = b - 7040; in = w2in; outp = w2tb; K = 1024; N = 512;  bx = id & 31; by = id >> 5; }
    int k0 = bx * 32, n0 = by * 32;
    int tx = threadIdx.x & 31, ty = threadIdx.x >> 5;
    #pragma unroll
    for (int i = 0; i < 32; i += 8)
      ts[ty + i][tx] = in[(size_t)(k0 + ty + i) * N + n0 + tx];
    __syncthreads();
    #pragma unroll
    for (int i = 0; i < 32; i += 8)
      outp[(size_t)(n0 + ty + i) * K + k0 + tx] = f2b(ts[tx][ty + i]);
  } else {
    int i = (b - 7552) * 256 + threadIdx.x;   // 16384 = d*16+s
    int s = i & 15;
    float v = alog[i];
    float base = alog[i - s];
    if (fabsf(v - (base + __logf((float)(s + 1)))) > 1e-4f) atomicOr(flag + 1, 1);
  }
}

// ---------------------------------------------------------------------------
// layernorms (C=512, one block/row, LDS tree; float2 loads, packed stores)
// ---------------------------------------------------------------------------
__global__ __launch_bounds__(256) void gather_ln1(const float* __restrict__ feat,
    const void* order, const float* __restrict__ w, const float* __restrict__ b,
    const int* flag, u16* __restrict__ x1b){
  __shared__ float rs_[256], rq_[256];
  const bool is64 = flag[0] != 0;
  int l = blockIdx.x, tid = threadIdx.x;
  int src = ldix(order, l, is64);
  float2 v = *(const float2*)(feat + (size_t)src * 512 + 2 * tid);
  rs_[tid] = v.x + v.y; rq_[tid] = v.x * v.x + v.y * v.y;
  __syncthreads();
  for (int o = 128; o; o >>= 1){
    if (tid < o){ rs_[tid] += rs_[tid + o]; rq_[tid] += rq_[tid + o]; }
    __syncthreads();
  }
  float mu = rs_[0] * (1.f / 512.f);
  float var = rq_[0] * (1.f / 512.f) - mu * mu;
  float rstd = rsqrtf(var + 1e-5f);
  float2 wv = *(const float2*)(w + 2 * tid);
  float2 bv = *(const float2*)(b + 2 * tid);
  unsigned pack = (unsigned)f2b((v.x - mu) * rstd * wv.x + bv.x)
                | ((unsigned)f2b((v.y - mu) * rstd * wv.y + bv.y) << 16);
  *(unsigned*)(x1b + (size_t)l * 512 + 2 * tid) = pack;
}

__global__ __launch_bounds__(256) void ln2_kernel(const float* __restrict__ x,
    const float* __restrict__ w, const float* __restrict__ b, u16* __restrict__ h2b){
  __shared__ float rs_[256], rq_[256];
  int l = blockIdx.x, tid = threadIdx.x;
  float2 v = *(const float2*)(x + (size_t)l * 512 + 2 * tid);
  rs_[tid] = v.x + v.y; rq_[tid] = v.x * v.x + v.y * v.y;
  __syncthreads();
  for (int o = 128; o; o >>= 1){
    if (tid < o){ rs_[tid] += rs_[tid + o]; rq_[tid] += rq_[tid + o]; }
    __syncthreads();
  }
  float mu = rs_[0] * (1.f / 512.f);
  float var = rq_[0] * (1.f / 512.f) - mu * mu;
  float rstd = rsqrtf(var + 1e-5f);
  float2 wv = *(const float2*)(w + 2 * tid);
  float2 bv = *(const float2*)(b + 2 * tid);
  unsigned pack = (unsigned)f2b((v.x - mu) * rstd * wv.x + bv.x)
                | ((unsigned)f2b((v.y - mu) * rstd * wv.y + bv.y) << 16);
  *(unsigned*)(h2b + (size_t)l * 512 + 2 * tid) = pack;
}

// ---------------------------------------------------------------------------
// depthwise causal conv (k=4) + silu -- vectorized rolling window.
// ---------------------------------------------------------------------------
__global__ __launch_bounds__(256) void conv_silu(const u16* __restrict__ xm,
    const float* __restrict__ cw, const float* __restrict__ cb, u16* __restrict__ xcb){
  constexpr int TT = 8;
  const int tid = threadIdx.x;
  const int d0 = (tid & 127) * 8;
  const int t0 = (blockIdx.x * 2 + (tid >> 7)) * TT;

  float wk[4][8], bias[8];
  #pragma unroll
  for (int j = 0; j < 8; j++) bias[j] = cb[d0 + j];
  #pragma unroll
  for (int j = 0; j < 8; j++){
    f32x4 v = *(const f32x4*)(cw + (d0 + j) * 4);
    wk[0][j] = v[0]; wk[1][j] = v[1]; wk[2][j] = v[2]; wk[3][j] = v[3];
  }

  float win[3][8];
  #pragma unroll
  for (int k = 0; k < 3; k++){
    int tt = t0 - 3 + k;
    if (tt >= 0){
      u16x8 v = *(const u16x8*)(xm + (size_t)tt * 1024 + d0);
      #pragma unroll
      for (int j = 0; j < 8; j++) win[k][j] = b2f(v[j]);
    } else {
      #pragma unroll
      for (int j = 0; j < 8; j++) win[k][j] = 0.f;
    }
  }

  #pragma unroll
  for (int t = 0; t < TT; t++){
    u16x8 v = *(const u16x8*)(xm + (size_t)(t0 + t) * 1024 + d0);
    u16x8 o;
    float cu[8];
    #pragma unroll
    for (int j = 0; j < 8; j++){
      cu[j] = b2f(v[j]);
      float acc = bias[j] + win[0][j] * wk[0][j] + win[1][j] * wk[1][j]
                + win[2][j] * wk[2][j] + cu[j] * wk[3][j];
      o[j] = f2b(siluf(acc));
    }
    *(u16x8*)(xcb + (size_t)(t0 + t) * 1024 + d0) = o;
    #pragma unroll
    for (int j = 0; j < 8; j++){
      win[0][j] = win[1][j]; win[1][j] = win[2][j]; win[2][j] = cu[j];
    }
  }
}

// ---------------------------------------------------------------------------
// bf16 MFMA GEMM, C = A (MxK, lda) * B^T (NxK, ldb), fused epilogues.
// ---------------------------------------------------------------------------
enum { M_BF16 = 0, M_INPROJ = 1, M_DT = 2, M_RES = 3, M_GELU = 4, M_FFN2S = 5 };

template<int MODE>
DEV void gemm_epilogue(float v, int m, int n, int N,
    float* __restrict__ outf, u16* __restrict__ outb, u16* __restrict__ outb2,
    const float* __restrict__ auxf, const float* __restrict__ auxw,
    const void* ordv, bool is64){
  size_t o = (size_t)m * N + n;
  if constexpr (MODE == M_BF16){
    outb[o] = f2b(v);
  } else if constexpr (MODE == M_INPROJ){
    if (n < 1024) outb [(size_t)m * 1024 + n]          = f2b(v);
    else          outb2[(size_t)m * 1024 + (n - 1024)] = f2b(siluf(v));
  } else if constexpr (MODE == M_DT){
    outb[o] = f2b(softplusf(v + auxw[n]));
  } else if constexpr (MODE == M_RES){
    int src = ldix(ordv, m, is64);
    outf[o] = v + auxw[(size_t)src * 512 + n];   // + feat[order[m]]
  } else if constexpr (MODE == M_GELU){
    outb[o] = f2b(geluf(v + auxw[n]));
  } else { // M_FFN2S: + bias + residual, scattered to out[order[m]] (R21:
           // out[i]=xfin[inverse[i]] == out[order[m]]=xfin[m])
    int dst = ldix(ordv, m, is64);
    outf[(size_t)dst * 512 + n] = v + auxw[n] + auxf[o];
  }
}

// ---------------------------------------------------------------------------
// 8-phase 256x256 GEMM (m201 template; refcheck'd R20). K%128==0, M%256==0,
// N%256==0. Stage-schedule ledger in R20 history.
// ---------------------------------------------------------------------------
#define PH8(BUF, MH, KS, LOADB, ...)                                        \
  do {                                                                      \
    bf16x8 af_[4];                                                          \
    _Pragma("unroll")                                                       \
    for (int mi = 0; mi < 4; mi++){                                         \
      int R = wr * 128 + (MH) * 64 + mi * 16 + rr;                          \
      int slot = ((KS) * 4 + qc) ^ (R & 7);                                 \
      af_[mi] = *(const bf16x8*)(&sA[BUF][R * 64 + slot * 8]);              \
    }                                                                       \
    if constexpr (LOADB){                                                   \
      _Pragma("unroll")                                                     \
      for (int nj = 0; nj < 4; nj++){                                       \
        int R = wc * 64 + nj * 16 + rr;                                     \
        int slot = ((KS) * 4 + qc) ^ (R & 7);                               \
        bfr[KS][nj] = *(const bf16x8*)(&sB[BUF][R * 64 + slot * 8]);        \
      }                                                                     \
    }                                                                       \
    __VA_ARGS__;                                                            \
    __builtin_amdgcn_s_barrier();                                           \
    asm volatile("s_waitcnt lgkmcnt(0)" ::: "memory");                      \
    __builtin_amdgcn_sched_barrier(0);                                      \
    __builtin_amdgcn_s_setprio(1);                                          \
    _Pragma("unroll")                                                       \
    for (int mi = 0; mi < 4; mi++)                                          \
      _Pragma("unroll")                                                     \
      for (int nj = 0; nj < 4; nj++)                                        \
        acc[(MH) * 4 + mi][nj] = __builtin_amdgcn_mfma_f32_16x16x32_bf16(   \
            af_[mi], bfr[KS][nj], acc[(MH) * 4 + mi][nj], 0, 0, 0);         \
    __builtin_amdgcn_s_setprio(0);                                          \
    __builtin_amdgcn_s_barrier();                                           \
  } while (0)

template<int MODE>
__global__ __launch_bounds__(512, 2) void gemm_8ph(
    const u16* __restrict__ A, const u16* __restrict__ B,
    int N, int K, int lda, int ldb,
    float* __restrict__ outf, u16* __restrict__ outb, u16* __restrict__ outb2,
    const float* __restrict__ auxf, const float* __restrict__ auxw,
    const void* ordv, const int* flag){
  __shared__ __align__(16) u16 sA[2][256 * 64];
  __shared__ __align__(16) u16 sB[2][256 * 64];
  const int tid  = threadIdx.x;
  const int wave = tid >> 6, lane = tid & 63;
  const int wr = wave >> 2, wc = wave & 3;
  const int m0 = blockIdx.x * 256, n0 = blockIdx.y * 256;
  const int rr = lane & 15, qc = lane >> 4;

  f32x4  acc[8][4] = {};
  bf16x8 bfr[2][4];

  const int srow = tid >> 3, ssub = tid & 7;
  auto stA = [&](int buf, int band, int kt){
    int row = band * 64 + srow;
    int cg = ssub ^ (row & 7);
    gld_lds16(A + (size_t)(m0 + row) * lda + kt * 64 + cg * 8,
              &sA[buf][band * 4096 + tid * 8]);
  };
  auto stB = [&](int buf, int band, int kt){
    int row = band * 64 + srow;
    int cg = ssub ^ (row & 7);
    gld_lds16(B + (size_t)(n0 + row) * ldb + kt * 64 + cg * 8,
              &sB[buf][band * 4096 + tid * 8]);
  };

  const int nst = K / 64, its = nst / 2;

  stA(0,0,0); stA(0,1,0); stA(0,2,0); stA(0,3,0);
  stB(0,0,0); stB(0,1,0); stB(0,2,0); stB(0,3,0);
  stB(1,0,1); stB(1,1,1); stB(1,2,1); stB(1,3,1);
  stA(1,0,1); stA(1,2,1);
  asm volatile("s_waitcnt vmcnt(6)" ::: "memory");
  __builtin_amdgcn_s_barrier();

  for (int it = 0; it < its; ++it){
    const int k2  = 2 * it + 1;
    const int kn1 = 2 * it + 2, kn2 = 2 * it + 3;
    const bool pre = (it + 1 < its);
    PH8(0, 0, 0, true,  stA(1,1,k2); stA(1,3,k2) );
    PH8(0, 0, 1, true,  ((void)0) );
    PH8(0, 1, 0, false, if (pre){ stB(0,0,kn1); stB(0,1,kn1); } );
    PH8(0, 1, 1, false,
        if (pre){ stB(0,2,kn1); stB(0,3,kn1); stA(0,0,kn1);
                  asm volatile("s_waitcnt vmcnt(5)" ::: "memory"); }
        else    { asm volatile("s_waitcnt vmcnt(0)" ::: "memory"); } );
    PH8(1, 0, 0, true,  if (pre){ stA(0,2,kn1); stA(0,1,kn1); stA(0,3,kn1); } );
    PH8(1, 0, 1, true,  ((void)0) );
    PH8(1, 1, 0, false, if (pre){ stB(1,0,kn2); stB(1,1,kn2); stB(1,2,kn2); } );
    PH8(1, 1, 1, false,
        if (pre){ stB(1,3,kn2); stA(1,0,kn2); stA(1,2,kn2);
                  asm volatile("s_waitcnt vmcnt(6)" ::: "memory"); } );
  }

  const bool is64 = flag ? (flag[0] != 0) : false;
  #pragma unroll
  for (int mi = 0; mi < 8; mi++)
    #pragma unroll
    for (int nj = 0; nj < 4; nj++)
      #pragma unroll
      for (int r = 0; r < 4; r++){
        int m = m0 + wr * 128 + mi * 16 + ((lane >> 4) << 2) + r;
        int n = n0 + wc * 64 + nj * 16 + (lane & 15);
        gemm_epilogue<MODE>(acc[mi][nj][r], m, n, N, outf, outb, outb2,
                            auxf, auxw, ordv, is64);
      }
}

// depth-2 pipelined GEMM (R17 schedule; geometry-parametric). 3 LDS buffers,
// counted vmcnt, 2-way LDS bijection (involution both-sides). K % 32 == 0.
template<int BM, int BN, int WM, int WN, int MODE>
__global__ __launch_bounds__((BM / WM) * (BN / WN) * 64) void gemm_p2(
    const u16* __restrict__ A, const u16* __restrict__ B,
    int N, int K, int lda, int ldb,
    float* __restrict__ outf, u16* __restrict__ outb, u16* __restrict__ outb2,
    const float* __restrict__ auxf, const float* __restrict__ auxw,
    const void* ordv, const int* flag){
  constexpr int BK = 32;
  constexpr int MI = WM / 16, NI = WN / 16;
  constexpr int WCOLS = BN / WN;
  constexpr int THREADS = (BM / WM) * (BN / WN) * 64;
  constexpr int NA = BM * BK / (THREADS * 8);
  constexpr int NB = BN * BK / (THREADS * 8);
  constexpr int LPS = NA + NB;
  static_assert(LPS == 2 || LPS == 3 || LPS == 4, "vmcnt literals");
  __shared__ __align__(16) u16 sA[3][BM * BK];
  __shared__ __align__(16) u16 sB[3][BN * BK];
  const int tid  = threadIdx.x;
  const int wave = tid >> 6, lane = tid & 63;
  const int wr = wave / WCOLS, wc = wave % WCOLS;
  const int m0 = blockIdx.x * BM, n0 = blockIdx.y * BN;
  const int rr = lane & 15;
  const int qc = lane >> 4;

  f32x4 acc[MI][NI] = {};

  auto stage = [&](int buf, int k0){
    #pragma unroll
    for (int i = 0; i < NA; i++){
      int idx = tid + i * THREADS;
      int row = idx >> 2, sub = idx & 3;
      int cg = (sub - (row >> 1)) & 3;
      gld_lds16(A + (size_t)(m0 + row) * lda + k0 + cg * 8, &sA[buf][idx * 8]);
    }
    #pragma unroll
    for (int i = 0; i < NB; i++){
      int idx = tid + i * THREADS;
      int row = idx >> 2, sub = idx & 3;
      int cg = (sub - (row >> 1)) & 3;
      gld_lds16(B + (size_t)(n0 + row) * ldb + k0 + cg * 8, &sB[buf][idx * 8]);
    }
  };

  const int nst = K / BK;
  stage(0, 0);
  if (nst > 1) stage(1, BK);
  for (int st = 0; st < nst; st++){
    if (st + 2 < nst) stage((st + 2) % 3, (st + 2) * BK);
    const int nf = (st + 2 < nst) ? 2 : ((st + 1 < nst) ? 1 : 0);
    if (nf == 2){
      if constexpr (LPS == 4)      asm volatile("s_waitcnt vmcnt(8)" ::: "memory");
      else if constexpr (LPS == 3) asm volatile("s_waitcnt vmcnt(6)" ::: "memory");
      else                         asm volatile("s_waitcnt vmcnt(4)" ::: "memory");
    } else if (nf == 1){
      if constexpr (LPS == 4)      asm volatile("s_waitcnt vmcnt(4)" ::: "memory");
      else if constexpr (LPS == 3) asm volatile("s_waitcnt vmcnt(3)" ::: "memory");
      else                         asm volatile("s_waitcnt vmcnt(2)" ::: "memory");
    } else {
      asm volatile("s_waitcnt vmcnt(0)" ::: "memory");
    }
    __builtin_amdgcn_s_barrier();
    __builtin_amdgcn_sched_barrier(0);

    const int cur = st % 3;
    bf16x8 af[MI], bfr[NI];
    #pragma unroll
    for (int i = 0; i < MI; i++){
      int R = wr * WM + i * 16 + rr;
      int slot = (qc + (R >> 1)) & 3;
      af[i] = *(const bf16x8*)(&sA[cur][R * BK + slot * 8]);
    }
    #pragma unroll
    for (int j = 0; j < NI; j++){
      int R = wc * WN + j * 16 + rr;
      int slot = (qc + (R >> 1)) & 3;
      bfr[j] = *(const bf16x8*)(&sB[cur][R * BK + slot * 8]);
    }
    #pragma unroll
    for (int i = 0; i < MI; i++)
      #pragma unroll
      for (int j = 0; j < NI; j++)
        acc[i][j] = __builtin_amdgcn_mfma_f32_16x16x32_bf16(af[i], bfr[j], acc[i][j], 0, 0, 0);

    asm volatile("s_waitcnt lgkmcnt(0)" ::: "memory");
    __builtin_amdgcn_s_barrier();
    __builtin_amdgcn_sched_barrier(0);
  }

  const bool is64 = flag ? (flag[0] != 0) : false;
  #pragma unroll
  for (int i = 0; i < MI; i++)
    #pragma unroll
    for (int j = 0; j < NI; j++)
      #pragma unroll
      for (int r = 0; r < 4; r++){
        int m = m0 + wr * WM + i * 16 + ((lane >> 4) << 2) + r;
        int n = n0 + wc * WN + j * 16 + (lane & 15);
        gemm_epilogue<MODE>(acc[i][j][r], m, n, N, outf, outb, outb2,
                            auxf, auxw, ordv, is64);
      }
}

// Legacy BK=32 single-buffer variant (dt_proj, K=32).
template<int BM, int BN, int WM, int WN, int MODE>
__global__ __launch_bounds__(256) void gemm_bt(
    const u16* __restrict__ A, const u16* __restrict__ B,
    int N, int K, int lda, int ldb,
    float* __restrict__ outf, u16* __restrict__ outb, u16* __restrict__ outb2,
    const float* __restrict__ auxf, const float* __restrict__ auxw,
    const void* ordv, const int* flag){
  constexpr int BK = 32;
  constexpr int MI = WM / 16, NI = WN / 16;
  constexpr int WCOLS = BN / WN;
  constexpr int NA = BM * 4 / 256;
  constexpr int NB = BN * 4 / 256;
  __shared__ __align__(16) u16 sA[BM * BK];
  __shared__ __align__(16) u16 sB[BN * BK];
  const int tid  = threadIdx.x;
  const int wave = tid >> 6, lane = tid & 63;
  const int wr = wave / WCOLS, wc = wave % WCOLS;
  const int m0 = blockIdx.x * BM, n0 = blockIdx.y * BN;
  const int rr = lane & 15;
  const int qk = (lane >> 4) * 8;

  f32x4 acc[MI][NI] = {};

  for (int k0 = 0; k0 < K; k0 += BK){
    #pragma unroll
    for (int i = 0; i < NA; i++){
      int idx = tid + i * 256;
      int r = idx >> 2, c = (idx & 3) * 8;
      gld_lds16(A + (size_t)(m0 + r) * lda + k0 + c, sA + (size_t)idx * 8);
    }
    #pragma unroll
    for (int i = 0; i < NB; i++){
      int idx = tid + i * 256;
      int r = idx >> 2, c = (idx & 3) * 8;
      gld_lds16(B + (size_t)(n0 + r) * ldb + k0 + c, sB + (size_t)idx * 8);
    }
    __syncthreads();

    bf16x8 af[MI], bfr[NI];
    #pragma unroll
    for (int i = 0; i < MI; i++)
      af[i] = *(const bf16x8*)(sA + (wr * WM + i * 16 + rr) * BK + qk);
    #pragma unroll
    for (int j = 0; j < NI; j++)
      bfr[j] = *(const bf16x8*)(sB + (wc * WN + j * 16 + rr) * BK + qk);
    #pragma unroll
    for (int i = 0; i < MI; i++)
      #pragma unroll
      for (int j = 0; j < NI; j++)
        acc[i][j] = __builtin_amdgcn_mfma_f32_16x16x32_bf16(af[i], bfr[j], acc[i][j], 0, 0, 0);
    __syncthreads();
  }

  const bool is64 = flag ? (flag[0] != 0) : false;
  #pragma unroll
  for (int i = 0; i < MI; i++)
    #pragma unroll
    for (int j = 0; j < NI; j++)
      #pragma unroll
      for (int r = 0; r < 4; r++){
        int m = m0 + wr * WM + i * 16 + ((lane >> 4) << 2) + r;
        int n = n0 + wc * WN + j * 16 + (lane & 15);
        gemm_epilogue<MODE>(acc[i][j][r], m, n, N, outf, outb, outb2,
                            auxf, auxw, ordv, is64);
      }
}

// ---------------------------------------------------------------------------
// chunked selective scan (fp32 state; chP/chH bf16, layout [chunk][s][d])
// ---------------------------------------------------------------------------
__global__ __launch_bounds__(256) void scan_pass1(const u16* __restrict__ dt,
    const u16* __restrict__ xc, const u16* __restrict__ dbc,
    const float* __restrict__ alog, const int* __restrict__ flag,
    u16* __restrict__ chP, u16* __restrict__ chH){
  __shared__ float sB[LC * 16];
  const int chunk = blockIdx.x;
  const int d = blockIdx.y * 256 + threadIdx.x;
  const int t0 = chunk * LC;
  for (int i = threadIdx.x; i < LC * 16; i += 256){
    int t = i >> 4, s = i & 15;
    sB[i] = b2f(dbc[(size_t)(t0 + t) * 64 + 32 + s]);
  }
  __syncthreads();
  float h[16];
  #pragma unroll
  for (int s = 0; s < 16; s++) h[s] = 0.f;
  float P[16];
  const bool fastA = (flag[1] == 0);
  if (fastA){
    const float a0 = -__expf(alog[(size_t)d * 16]);
    float R = 1.f;
    for (int t = 0; t < LC; t++){
      float dtv = b2f(dt[(size_t)(t0 + t) * 1024 + d]);
      float xv  = b2f(xc[(size_t)(t0 + t) * 1024 + d]);
      float dtx = dtv * xv;
      float r = __expf(dtv * a0);
      R *= r;
      float a_[16];
      pow16(r, a_);
      #pragma unroll
      for (int s = 0; s < 16; s++)
        h[s] = a_[s] * h[s] + dtx * sB[t * 16 + s];
    }
    pow16(R, P);
  } else {
    float A[16];
    #pragma unroll
    for (int s = 0; s < 16; s++){
      A[s] = -__expf(alog[(size_t)d * 16 + s]);
      P[s] = 1.f;
    }
    for (int t = 0; t < LC; t++){
      float dtv = b2f(dt[(size_t)(t0 + t) * 1024 + d]);
      float xv  = b2f(xc[(size_t)(t0 + t) * 1024 + d]);
      float dtx = dtv * xv;
      #pragma unroll
      for (int s = 0; s < 16; s++){
        float a = __expf(dtv * A[s]);
        P[s] *= a;
        h[s] = a * h[s] + dtx * sB[t * 16 + s];
      }
    }
  }
  #pragma unroll
  for (int s = 0; s < 16; s++){
    chP[((size_t)chunk * 16 + s) * 1024 + d] = f2b(P[s]);
    chH[((size_t)chunk * 16 + s) * 1024 + d] = f2b(h[s]);
  }
}

// hin may alias chP: window loads 16 ahead into regs before storing (R21:
// window 8->16 for 2x memory-level parallelism; 1 wave/SIMD occupancy).
__global__ __launch_bounds__(64) void carry_scan(const u16* chP, const u16* chH,
                                                 u16* hin){
  int id = blockIdx.x * 64 + threadIdx.x;   // id = s*1024 + d
  float h = 0.f;
  for (int k = 0; k < NCH; k += 16){
    float P[16], E[16];
    #pragma unroll
    for (int j = 0; j < 16; j++){
      P[j] = b2f(chP[(size_t)(k + j) * 16384 + id]);
      E[j] = b2f(chH[(size_t)(k + j) * 16384 + id]);
    }
    #pragma unroll
    for (int j = 0; j < 16; j++){
      hin[(size_t)(k + j) * 16384 + id] = f2b(h);
      h = P[j] * h + E[j];
    }
  }
}

__global__ __launch_bounds__(256) void scan_pass3(const u16* __restrict__ dt,
    const u16* xc, const u16* __restrict__ dbc,
    const float* __restrict__ alog, const int* __restrict__ flag,
    const u16* __restrict__ hin,
    const float* __restrict__ dskip, const u16* __restrict__ zsil, u16* yb){
  __shared__ float sBC[LC * 32];
  const int chunk = blockIdx.x;
  const int d = blockIdx.y * 256 + threadIdx.x;
  const int t0 = chunk * LC;
  for (int i = threadIdx.x; i < LC * 32; i += 256){
    int t = i >> 5, c = i & 31;
    sBC[i] = b2f(dbc[(size_t)(t0 + t) * 64 + 32 + c]);
  }
  __syncthreads();
  float h[16];
  #pragma unroll
  for (int s = 0; s < 16; s++)
    h[s] = b2f(hin[((size_t)chunk * 16 + s) * 1024 + d]);
  const float Dv = dskip[d];
  const bool fastA = (flag[1] == 0);
  if (fastA){
    const float a0 = -__expf(alog[(size_t)d * 16]);
    for (int t = 0; t < LC; t++){
      float dtv = b2f(dt[(size_t)(t0 + t) * 1024 + d]);
      float xv  = b2f(xc[(size_t)(t0 + t) * 1024 + d]);
      float dtx = dtv * xv;
      float r = __expf(dtv * a0);
      float a_[16];
      pow16(r, a_);
      float y = 0.f;
      #pragma unroll
      for (int s = 0; s < 16; s++){
        h[s] = a_[s] * h[s] + dtx * sBC[t * 32 + s];
        y += h[s] * sBC[t * 32 + 16 + s];
      }
      float rv = (y + xv * Dv) * b2f(zsil[(size_t)(t0 + t) * 1024 + d]);
      yb[(size_t)(t0 + t) * 1024 + d] = f2b(rv);
    }
  } else {
    float A[16];
    #pragma unroll
    for (int s = 0; s < 16; s++) A[s] = -__expf(alog[(size_t)d * 16 + s]);
    for (int t = 0; t < LC; t++){
      float dtv = b2f(dt[(size_t)(t0 + t) * 1024 + d]);
      float xv  = b2f(xc[(size_t)(t0 + t) * 1024 + d]);
      float dtx = dtv * xv;
      float y = 0.f;
      #pragma unroll
      for (int s = 0; s < 16; s++){
        float a = __expf(dtv * A[s]);
        h[s] = a * h[s] + dtx * sBC[t * 32 + s];
        y += h[s] * sBC[t * 32 + 16 + s];
      }
      float rv = (y + xv * Dv) * b2f(zsil[(size_t)(t0 + t) * 1024 + d]);
      yb[(size_t)(t0 + t) * 1024 + d] = f2b(rv);
    }
  }
}

// ---------------------------------------------------------------------------
extern "C" void kernel_launch(void* const* d_in, const int* in_sizes, int n_in,
                              void* d_out, int out_size, void* d_ws, size_t ws_size,
                              hipStream_t stream){
  float* out = (float*)d_out;
  char* w = (char*)d_ws;

  constexpr size_t OFF_W1T  = 3342336;
  constexpr size_t OFF_W2T  = OFF_W1T + 1048576;
  constexpr size_t OFF_FLAG = OFF_W2T + 1048576;
  constexpr size_t OFF_XMB  = 5439744;               // 32MiB xmb / dtb / x(fp32)
  constexpr size_t OFF_ZSIL = OFF_XMB  + 33554432;   // 32MiB zsil / midb
  constexpr size_t OFF_XCB  = OFF_ZSIL + 33554432;   // 32MiB xcb / yb
  constexpr size_t OFF_X1B  = OFF_XCB  + 33554432;   // 16MiB x1b / h2b / chP+chH
  constexpr size_t OFF_DBC  = OFF_X1B  + 16777216;   //  2MiB
  constexpr size_t OFF_CHP  = OFF_X1B;               //  8MiB (over dead x1b)
  constexpr size_t OFF_CHH  = OFF_X1B  + 8388608;    //  8MiB
  constexpr size_t WS_NEED  = OFF_DBC  + 2097152;

  int code = 0;
  static const int want[20] = {8388608,16384,16384,512,512,1048576,4096,1024,
                               65536,32768,1024,16384,1024,524288,512,512,
                               524288,1024,524288,512};
  if (n_in != 20) code = 1000;
  else {
    for (int i = 0; i < 20 && !code; i++)
      if (in_sizes[i] != want[i]) code = 2000 + i * 50;
    if (!code && out_size != 8388608) code = 3000;
    if (!code && ws_size < WS_NEED)   code = 4000;
  }
  if (code){
    unsigned n = (unsigned)(out_size > 0 ? out_size : 1);
    fill_k<<<(n + 255) / 256, 256, 0, stream>>>(out, (float)code, n);
    return;
  }

  u16*   w1tb = (u16*)(w + OFF_W1T);
  u16*   w2tb = (u16*)(w + OFF_W2T);
  int*   flag = (int*)(w + OFF_FLAG);
  u16*   xmb  = (u16*)(w + OFF_XMB);
  u16*   zsil = (u16*)(w + OFF_ZSIL);
  u16*   xcb  = (u16*)(w + OFF_XCB);
  u16*   x1b  = (u16*)(w + OFF_X1B);
  u16*   dbcb = (u16*)(w + OFF_DBC);
  u16*   chP  = (u16*)(w + OFF_CHP);
  u16*   chH  = (u16*)(w + OFF_CHH);
  float* x    = (float*)(w + OFF_XMB);   // fp32 residual over dead dtb
  u16* dtb  = xmb;   // xmb dead after conv
  u16* yb   = xcb;   // pass3: read-before-write per element
  u16* midb = zsil;  // zsil dead after pass3
  u16* h2b  = x1b;   // x1b dead after in_proj (chP/chH dead after pass3)
  u16* hin  = chP;   // carry: read-before-write per window

  u16* nb = (u16*)w;
  u16* inpjn  = nb;
  u16* xpjn   = nb + 1048576;
  u16* dtpjn  = nb + 1114112;
  u16* outpjn = nb + 1146880;
  NT4 t;
  t.src[0] = (const float*)d_in[5];  t.src[1] = (const float*)d_in[8];
  t.src[2] = (const float*)d_in[9];  t.src[3] = (const float*)d_in[13];
  t.off[0] = 0; t.off[1] = 1048576; t.off[2] = 1114112; t.off[3] = 1146880; t.off[4] = 1671168;

  // 0. detect (zeroes flag[1] BEFORE prep_k's checkA atomicOr) + fused prep
  detect_k<<<1, 1, 0, stream>>>((const int*)d_in[1], flag);
  prep_k<<<7616, 256, 0, stream>>>(t, nb,
      (const float*)d_in[16], w1tb, (const float*)d_in[18], w2tb,
      (const float*)d_in[11], flag);

  // 1. gather + LN1
  gather_ln1<<<L_SEQ, 256, 0, stream>>>((const float*)d_in[0], d_in[1],
      (const float*)d_in[3], (const float*)d_in[4], flag, x1b);

  // 2. in_proj -> xmb | silu(z)   (K=512: 8-phase, 512 blocks)
  gemm_8ph<M_INPROJ><<<dim3(64,8),512,0,stream>>>(
      x1b, inpjn, 2048, 512, 512, 512, nullptr, xmb, zsil, nullptr, nullptr, nullptr, nullptr);

  // 3. conv + silu
  conv_silu<<<1024, 256, 0, stream>>>(xmb,
      (const float*)d_in[6], (const float*)d_in[7], xcb);

  // 4. x_proj -> dbcb   (K=1024; 64x64 p2)
  gemm_p2<64,64,16,64,M_BF16><<<dim3(256,1),256,0,stream>>>(
      xcb, xpjn, 64, 1024, 1024, 1024, nullptr, dbcb, nullptr, nullptr, nullptr, nullptr, nullptr);

  // 5. dt_proj + softplus -> dtb  (K=32: legacy)
  gemm_bt<128,128,64,64,M_DT><<<dim3(128,8),256,0,stream>>>(
      dbcb, dtpjn, 1024, 32, 64, 32, nullptr, dtb, nullptr, nullptr,
      (const float*)d_in[10], nullptr, nullptr);

  // 6. chunked scan
  scan_pass1<<<dim3(NCH,4),256,0,stream>>>(dtb, xcb, dbcb,
      (const float*)d_in[11], flag, chP, chH);
  carry_scan<<<256,64,0,stream>>>(chP, chH, hin);
  scan_pass3<<<dim3(NCH,4),256,0,stream>>>(dtb, xcb, dbcb,
      (const float*)d_in[11], flag, hin, (const float*)d_in[12], zsil, yb);

  // 7. out_proj + feat[order[m]] residual -> x (fp32)  (K=1024; 256x128 p2)
  gemm_p2<256,128,64,64,M_RES><<<dim3(64,4),512,0,stream>>>(
      yb, outpjn, 512, 1024, 1024, 1024, x, nullptr, nullptr, nullptr,
      (const float*)d_in[0], d_in[1], flag);

  // 8. LN2 -> h2b
  ln2_kernel<<<L_SEQ,256,0,stream>>>(x, (const float*)d_in[14], (const float*)d_in[15], h2b);

  // 9. FFN1 + gelu -> midb  (K=512: 8-phase, 256 blocks = 1/CU)
  gemm_8ph<M_GELU><<<dim3(64,4),512,0,stream>>>(
      h2b, w1tb, 1024, 512, 512, 512, nullptr, midb, nullptr, nullptr,
      (const float*)d_in[17], nullptr, nullptr);

  // 10. FFN2 + bias + residual, scattered straight to d_out at row order[m]
  //     (R21: replaces xfin materialization + final_gather kernel)
  gemm_p2<256,128,64,64,M_FFN2S><<<dim3(64,4),512,0,stream>>>(
      midb, w2tb, 512, 1024, 1024, 1024, out, nullptr, nullptr, x,
      (const float*)d_in[19], d_in[1], flag);
}